// Round 1
// baseline (966.218 us; speedup 1.0000x reference)
//
#include <hip/hip_runtime.h>

#define NN 100000
#define EE 3200000
#define NF 256
#define NH 128
#define NC 16
#define NB_SCAN 98   // ceil(NN/1024)

typedef __bf16 bf16;
typedef bf16 bf16x2 __attribute__((ext_vector_type(2)));
typedef bf16 bf16x8 __attribute__((ext_vector_type(8)));
typedef float f32x4 __attribute__((ext_vector_type(4)));

// ---------------- CSR build ----------------

__global__ void k_hist(const int* __restrict__ dst, int* __restrict__ cnt) {
    int e = blockIdx.x * 256 + threadIdx.x;
    if (e < EE) atomicAdd(&cnt[dst[e]], 1);
}

__global__ void k_scan1(const int* __restrict__ cnt, int* __restrict__ row_off,
                        int* __restrict__ bsum) {
    __shared__ int s[256];
    int t = threadIdx.x;
    int base = blockIdx.x * 1024 + t * 4;
    int v0 = 0, v1 = 0, v2 = 0, v3 = 0;
    if (base + 3 < NN) {
        int4 c = *(const int4*)(cnt + base);
        v0 = c.x; v1 = c.y; v2 = c.z; v3 = c.w;
    } else {
        if (base     < NN) v0 = cnt[base];
        if (base + 1 < NN) v1 = cnt[base + 1];
        if (base + 2 < NN) v2 = cnt[base + 2];
        if (base + 3 < NN) v3 = cnt[base + 3];
    }
    int tsum = v0 + v1 + v2 + v3;
    s[t] = tsum;
    __syncthreads();
    for (int off = 1; off < 256; off <<= 1) {
        int xv = (t >= off) ? s[t - off] : 0;
        __syncthreads();
        s[t] += xv;
        __syncthreads();
    }
    if (t == 255) bsum[blockIdx.x] = s[255];
    int e0 = s[t] - tsum;
    int e1 = e0 + v0, e2 = e1 + v1, e3 = e2 + v2;
    if (base     < NN) row_off[base]     = e0;
    if (base + 1 < NN) row_off[base + 1] = e1;
    if (base + 2 < NN) row_off[base + 2] = e2;
    if (base + 3 < NN) row_off[base + 3] = e3;
}

__global__ void k_scan2(int* __restrict__ bsum) {
    __shared__ int s[128];
    int t = threadIdx.x;
    int v = (t < NB_SCAN) ? bsum[t] : 0;
    s[t] = v;
    __syncthreads();
    for (int off = 1; off < 128; off <<= 1) {
        int xv = (t >= off) ? s[t - off] : 0;
        __syncthreads();
        s[t] += xv;
        __syncthreads();
    }
    if (t < NB_SCAN) bsum[t] = s[t] - v;  // exclusive block offsets
}

__global__ void k_scan3(int* __restrict__ row_off, int* __restrict__ cursor,
                        const int* __restrict__ bsum) {
    int t = threadIdx.x;
    int add = bsum[blockIdx.x];
    int base = blockIdx.x * 1024 + t * 4;
#pragma unroll
    for (int j = 0; j < 4; j++) {
        int i = base + j;
        if (i < NN) {
            int v = row_off[i] + add;
            row_off[i] = v;
            cursor[i] = v;
        }
    }
    if (blockIdx.x == 0 && t == 0) row_off[NN] = EE;
}

__global__ void k_fill(const int* __restrict__ src, const int* __restrict__ dst,
                       const float* __restrict__ ew, int* __restrict__ cursor,
                       int* __restrict__ ssrc, float* __restrict__ sw) {
    int e = blockIdx.x * 256 + threadIdx.x;
    if (e >= EE) return;
    int d = dst[e];
    int p = atomicAdd(&cursor[d], 1);
    ssrc[p] = src[e];
    sw[p] = ew[e];
}

// ---------------- layer 1: x @ W1 (bf16 MFMA) ----------------

__global__ void k_cvtW1(const float* __restrict__ W1, bf16* __restrict__ W1T) {
    int i = blockIdx.x * 256 + threadIdx.x;  // 32768 elems, W1 is [NF][NH]
    int k = i >> 7, n = i & 127;
    W1T[n * NF + k] = (bf16)W1[i];           // W1T: [NH][NF] (B transposed for b128 frag reads)
}

__global__ __launch_bounds__(256, 1) void k_gemm1(const float* __restrict__ x,
                                                  const bf16* __restrict__ W1T,
                                                  bf16* __restrict__ h0) {
    int lane = threadIdx.x & 63;
    int wid = threadIdx.x >> 6;
    int m = lane & 15;     // A row / D col within 16-tile
    int kg = lane >> 4;    // k-group 0..3
    int row = blockIdx.x * 64 + wid * 16 + m;
    bool in = (row < NN);
    const float* xr = x + (size_t)row * NF;

    // A fragments for the full K=256 (8 k-tiles of 32), converted fp32->bf16
    bf16x8 a[8];
#pragma unroll
    for (int kt = 0; kt < 8; kt++) {
        int k0 = kt * 32 + kg * 8;
        float4 u = in ? *(const float4*)(xr + k0)     : make_float4(0.f, 0.f, 0.f, 0.f);
        float4 v = in ? *(const float4*)(xr + k0 + 4) : make_float4(0.f, 0.f, 0.f, 0.f);
        bf16x8 av = { (bf16)u.x, (bf16)u.y, (bf16)u.z, (bf16)u.w,
                      (bf16)v.x, (bf16)v.y, (bf16)v.z, (bf16)v.w };
        a[kt] = av;
    }

    f32x4 acc[8] = {};
#pragma unroll
    for (int ct = 0; ct < 8; ct++) {  // 8 col tiles of 16 -> 128 cols
        const bf16* bp = W1T + (size_t)(ct * 16 + m) * NF + kg * 8;
#pragma unroll
        for (int kt = 0; kt < 8; kt++) {
            bf16x8 b = *(const bf16x8*)(bp + kt * 32);
            acc[ct] = __builtin_amdgcn_mfma_f32_16x16x32_bf16(a[kt], b, acc[ct], 0, 0, 0);
        }
    }

    // D layout: col = lane&15, row = (lane>>4)*4 + reg
    int rbase = blockIdx.x * 64 + wid * 16 + kg * 4;
#pragma unroll
    for (int ct = 0; ct < 8; ct++) {
        int col = ct * 16 + m;
#pragma unroll
        for (int r = 0; r < 4; r++) {
            int rr = rbase + r;
            if (rr < NN) h0[(size_t)rr * NH + col] = (bf16)acc[ct][r];
        }
    }
}

// ---------------- spmm1: h = relu(A @ h0 + b1), one wave per node ----------------

__global__ void k_spmm1(const int* __restrict__ row_off, const int* __restrict__ ssrc,
                        const float* __restrict__ sw, const bf16* __restrict__ h0,
                        const float* __restrict__ b1, bf16* __restrict__ h) {
    int gw = (blockIdx.x * 256 + threadIdx.x) >> 6;  // node
    int lane = threadIdx.x & 63;
    if (gw >= NN) return;
    int s = row_off[gw], e = row_off[gw + 1];
    float a0 = 0.f, a1 = 0.f;
    for (int i = s; i < e; i++) {
        int sr = ssrc[i];    // wave-uniform -> s_load
        float w = sw[i];
        bf16x2 hv = *(const bf16x2*)(h0 + (size_t)sr * NH + lane * 2);
        a0 += w * (float)hv[0];
        a1 += w * (float)hv[1];
    }
    a0 = fmaxf(a0 + b1[lane * 2],     0.f);
    a1 = fmaxf(a1 + b1[lane * 2 + 1], 0.f);
    bf16x2 o = { (bf16)a0, (bf16)a1 };
    *(bf16x2*)(h + (size_t)gw * NH + lane * 2) = o;
}

// ---------------- gemm2: g = h @ W2, one thread per row ----------------

__global__ __launch_bounds__(256) void k_gemm2(const bf16* __restrict__ h,
                                               const float* __restrict__ W2,
                                               float* __restrict__ g) {
    __shared__ float sW[NH * NC];
    int t = threadIdx.x;
    for (int i = t; i < NH * NC; i += 256) sW[i] = W2[i];
    __syncthreads();
    int row = blockIdx.x * 256 + t;
    if (row >= NN) return;
    const bf16* hr = h + (size_t)row * NH;
    float acc[NC] = {};
    for (int kc = 0; kc < NH / 8; kc++) {
        bf16x8 hv = *(const bf16x8*)(hr + kc * 8);
#pragma unroll
        for (int j = 0; j < 8; j++) {
            float hx = (float)hv[j];
            const float* wr = &sW[(kc * 8 + j) * NC];
#pragma unroll
            for (int c = 0; c < NC; c++) acc[c] += hx * wr[c];
        }
    }
    float4* go = (float4*)(g + (size_t)row * NC);
    go[0] = make_float4(acc[0], acc[1], acc[2], acc[3]);
    go[1] = make_float4(acc[4], acc[5], acc[6], acc[7]);
    go[2] = make_float4(acc[8], acc[9], acc[10], acc[11]);
    go[3] = make_float4(acc[12], acc[13], acc[14], acc[15]);
}

// ---------------- spmm2: logits = A @ g + b2, 16 lanes per node ----------------

__global__ void k_spmm2(const int* __restrict__ row_off, const int* __restrict__ ssrc,
                        const float* __restrict__ sw, const float* __restrict__ g,
                        const float* __restrict__ b2, float* __restrict__ out) {
    int t = blockIdx.x * 256 + threadIdx.x;
    int node = t >> 4, c = t & 15;
    if (node >= NN) return;
    int s = row_off[node], e = row_off[node + 1];
    float acc = b2[c];
    for (int i = s; i < e; i++) {
        acc += sw[i] * g[(size_t)ssrc[i] * NC + c];
    }
    out[t] = acc;  // t == node*16 + c
}

// ---------------- log_softmax in place over 16 classes ----------------

__global__ void k_lsm(float* __restrict__ out) {
    int t = blockIdx.x * 256 + threadIdx.x;  // grid sized exactly NN*NC/256
    float v = out[t];
    float m = v;
#pragma unroll
    for (int off = 1; off < 16; off <<= 1) m = fmaxf(m, __shfl_xor(m, off));
    float ex = __expf(v - m);
    float sum = ex;
#pragma unroll
    for (int off = 1; off < 16; off <<= 1) sum += __shfl_xor(sum, off);
    out[t] = v - m - __logf(sum);
}

// ---------------- launch ----------------

extern "C" void kernel_launch(void* const* d_in, const int* in_sizes, int n_in,
                              void* d_out, int out_size, void* d_ws, size_t ws_size,
                              hipStream_t stream) {
    const float* x  = (const float*)d_in[0];
    const float* W1 = (const float*)d_in[1];
    const float* b1 = (const float*)d_in[2];
    const float* W2 = (const float*)d_in[3];
    const float* b2 = (const float*)d_in[4];
    const float* ew = (const float*)d_in[5];
    const int* src  = (const int*)d_in[6];
    const int* dst  = (const int*)d_in[7];
    float* out = (float*)d_out;

    char* ws = (char*)d_ws;
    // workspace layout (all offsets 16B aligned), total ~84.1 MB
    bf16*  h0      = (bf16*)(ws + 0);              // NN*NH*2 = 25,600,000
    bf16*  h       = (bf16*)(ws + 25600000);       // 25,600,000
    float* g       = (float*)(ws + 51200000);      // NN*NC*4 = 6,400,000
    int*   row_off = (int*)(ws + 57600000);        // (NN+1)*4 -> 400,016
    int*   cursor  = (int*)(ws + 58000016);        // NN*4 = 400,000 (also the histogram)
    int*   bsum    = (int*)(ws + 58400016);        // 512
    int*   ssrc    = (int*)(ws + 58400528);        // EE*4 = 12,800,000
    float* swgt    = (float*)(ws + 71200528);      // EE*4 = 12,800,000
    bf16*  W1T     = (bf16*)(ws + 84000528);       // NF*NH*2 = 65,536

    // CSR build (per call: ws is re-poisoned every launch)
    hipMemsetAsync(cursor, 0, NN * sizeof(int), stream);
    k_hist<<<EE / 256, 256, 0, stream>>>(dst, cursor);
    k_scan1<<<NB_SCAN, 256, 0, stream>>>(cursor, row_off, bsum);
    k_scan2<<<1, 128, 0, stream>>>(bsum);
    k_scan3<<<NB_SCAN, 256, 0, stream>>>(row_off, cursor, bsum);
    k_fill<<<EE / 256, 256, 0, stream>>>(src, dst, ew, cursor, ssrc, swgt);

    // layer 1
    k_cvtW1<<<(NF * NH) / 256, 256, 0, stream>>>(W1, W1T);
    k_gemm1<<<(NN + 63) / 64, 256, 0, stream>>>(x, W1T, h0);
    k_spmm1<<<(NN * 64) / 256, 256, 0, stream>>>(row_off, ssrc, swgt, h0, b1, h);

    // layer 2
    k_gemm2<<<(NN + 255) / 256, 256, 0, stream>>>(h, W2, g);
    k_spmm2<<<(NN * 16) / 256, 256, 0, stream>>>(row_off, ssrc, swgt, g, b2, out);
    k_lsm<<<(NN * 16) / 256, 256, 0, stream>>>(out);
}

// Round 2
// 828.307 us; speedup vs baseline: 1.1665x; 1.1665x over previous
//
#include <hip/hip_runtime.h>

#define NN 100000
#define EE 3200000
#define NF 256
#define NH 128
#define NC 16
#define NB_SCAN 98   // ceil(NN/1024)

typedef __bf16 bf16;
typedef bf16 bf16x2 __attribute__((ext_vector_type(2)));
typedef bf16 bf16x8 __attribute__((ext_vector_type(8)));
typedef float f32x4 __attribute__((ext_vector_type(4)));

// ---------------- CSR build ----------------

__global__ void k_hist(const int* __restrict__ dst, int* __restrict__ cnt) {
    int e = blockIdx.x * 256 + threadIdx.x;
    if (e < EE) atomicAdd(&cnt[dst[e]], 1);
}

__global__ void k_scan1(const int* __restrict__ cnt, int* __restrict__ row_off,
                        int* __restrict__ bsum) {
    __shared__ int s[256];
    int t = threadIdx.x;
    int base = blockIdx.x * 1024 + t * 4;
    int v0 = 0, v1 = 0, v2 = 0, v3 = 0;
    if (base + 3 < NN) {
        int4 c = *(const int4*)(cnt + base);
        v0 = c.x; v1 = c.y; v2 = c.z; v3 = c.w;
    } else {
        if (base     < NN) v0 = cnt[base];
        if (base + 1 < NN) v1 = cnt[base + 1];
        if (base + 2 < NN) v2 = cnt[base + 2];
        if (base + 3 < NN) v3 = cnt[base + 3];
    }
    int tsum = v0 + v1 + v2 + v3;
    s[t] = tsum;
    __syncthreads();
    for (int off = 1; off < 256; off <<= 1) {
        int xv = (t >= off) ? s[t - off] : 0;
        __syncthreads();
        s[t] += xv;
        __syncthreads();
    }
    if (t == 255) bsum[blockIdx.x] = s[255];
    int e0 = s[t] - tsum;
    int e1 = e0 + v0, e2 = e1 + v1, e3 = e2 + v2;
    if (base     < NN) row_off[base]     = e0;
    if (base + 1 < NN) row_off[base + 1] = e1;
    if (base + 2 < NN) row_off[base + 2] = e2;
    if (base + 3 < NN) row_off[base + 3] = e3;
}

__global__ void k_scan2(int* __restrict__ bsum) {
    __shared__ int s[128];
    int t = threadIdx.x;
    int v = (t < NB_SCAN) ? bsum[t] : 0;
    s[t] = v;
    __syncthreads();
    for (int off = 1; off < 128; off <<= 1) {
        int xv = (t >= off) ? s[t - off] : 0;
        __syncthreads();
        s[t] += xv;
        __syncthreads();
    }
    if (t < NB_SCAN) bsum[t] = s[t] - v;  // exclusive block offsets
}

__global__ void k_scan3(int* __restrict__ row_off, int* __restrict__ cursor,
                        const int* __restrict__ bsum) {
    int t = threadIdx.x;
    int add = bsum[blockIdx.x];
    int base = blockIdx.x * 1024 + t * 4;
#pragma unroll
    for (int j = 0; j < 4; j++) {
        int i = base + j;
        if (i < NN) {
            int v = row_off[i] + add;
            row_off[i] = v;
            cursor[i] = v;
        }
    }
    if (blockIdx.x == 0 && t == 0) row_off[NN] = EE;
}

__global__ void k_fill(const int* __restrict__ src, const int* __restrict__ dst,
                       const float* __restrict__ ew, int* __restrict__ cursor,
                       int2* __restrict__ edges) {
    int e = blockIdx.x * 256 + threadIdx.x;
    if (e >= EE) return;
    int d = dst[e];
    int p = atomicAdd(&cursor[d], 1);
    edges[p] = make_int2(src[e], __float_as_int(ew[e]));  // one 8B store
}

// ---------------- layer 1: x @ W1 (bf16 MFMA) ----------------

__global__ void k_cvtW1(const float* __restrict__ W1, bf16* __restrict__ W1T) {
    int i = blockIdx.x * 256 + threadIdx.x;  // 32768 elems, W1 is [NF][NH]
    int k = i >> 7, n = i & 127;
    W1T[n * NF + k] = (bf16)W1[i];           // W1T: [NH][NF]
}

__global__ __launch_bounds__(256, 1) void k_gemm1(const float* __restrict__ x,
                                                  const bf16* __restrict__ W1T,
                                                  bf16* __restrict__ h0) {
    int lane = threadIdx.x & 63;
    int wid = threadIdx.x >> 6;
    int m = lane & 15;     // A row / D col within 16-tile
    int kg = lane >> 4;    // k-group 0..3
    int row = blockIdx.x * 64 + wid * 16 + m;
    bool in = (row < NN);
    const float* xr = x + (size_t)row * NF;

    bf16x8 a[8];
#pragma unroll
    for (int kt = 0; kt < 8; kt++) {
        int k0 = kt * 32 + kg * 8;
        float4 u = in ? *(const float4*)(xr + k0)     : make_float4(0.f, 0.f, 0.f, 0.f);
        float4 v = in ? *(const float4*)(xr + k0 + 4) : make_float4(0.f, 0.f, 0.f, 0.f);
        bf16x8 av = { (bf16)u.x, (bf16)u.y, (bf16)u.z, (bf16)u.w,
                      (bf16)v.x, (bf16)v.y, (bf16)v.z, (bf16)v.w };
        a[kt] = av;
    }

    f32x4 acc[8] = {};
#pragma unroll
    for (int ct = 0; ct < 8; ct++) {
        const bf16* bp = W1T + (size_t)(ct * 16 + m) * NF + kg * 8;
#pragma unroll
        for (int kt = 0; kt < 8; kt++) {
            bf16x8 b = *(const bf16x8*)(bp + kt * 32);
            acc[ct] = __builtin_amdgcn_mfma_f32_16x16x32_bf16(a[kt], b, acc[ct], 0, 0, 0);
        }
    }

    // D layout: col = lane&15, row = (lane>>4)*4 + reg
    int rbase = blockIdx.x * 64 + wid * 16 + kg * 4;
#pragma unroll
    for (int ct = 0; ct < 8; ct++) {
        int col = ct * 16 + m;
#pragma unroll
        for (int r = 0; r < 4; r++) {
            int rr = rbase + r;
            if (rr < NN) h0[(size_t)rr * NH + col] = (bf16)acc[ct][r];
        }
    }
}

// ---------------- spmm1: h = relu(A @ h0 + b1) ----------------
// one wave per node, 8 edges in flight (independent accumulators)

__global__ void k_spmm1(const int* __restrict__ row_off, const int2* __restrict__ edges,
                        const bf16* __restrict__ h0, const float* __restrict__ b1,
                        bf16* __restrict__ h) {
    int gw = (blockIdx.x * 256 + threadIdx.x) >> 6;  // node
    int lane = threadIdx.x & 63;
    if (gw >= NN) return;
    int s = row_off[gw], e = row_off[gw + 1];

    float ax[8], ay[8];
#pragma unroll
    for (int j = 0; j < 8; j++) { ax[j] = 0.f; ay[j] = 0.f; }

    int i = s;
    for (; i + 8 <= e; i += 8) {
        int2 r[8];
#pragma unroll
        for (int j = 0; j < 8; j++) r[j] = edges[i + j];
#pragma unroll
        for (int j = 0; j < 8; j++) {
            bf16x2 hv = *(const bf16x2*)(h0 + (size_t)r[j].x * NH + lane * 2);
            float w = __int_as_float(r[j].y);
            ax[j] += w * (float)hv[0];
            ay[j] += w * (float)hv[1];
        }
    }
    for (; i < e; i++) {
        int2 r = edges[i];
        bf16x2 hv = *(const bf16x2*)(h0 + (size_t)r.x * NH + lane * 2);
        float w = __int_as_float(r.y);
        ax[0] += w * (float)hv[0];
        ay[0] += w * (float)hv[1];
    }
    float sx = ((ax[0] + ax[1]) + (ax[2] + ax[3])) + ((ax[4] + ax[5]) + (ax[6] + ax[7]));
    float sy = ((ay[0] + ay[1]) + (ay[2] + ay[3])) + ((ay[4] + ay[5]) + (ay[6] + ay[7]));
    sx = fmaxf(sx + b1[lane * 2],     0.f);
    sy = fmaxf(sy + b1[lane * 2 + 1], 0.f);
    bf16x2 o = { (bf16)sx, (bf16)sy };
    *(bf16x2*)(h + (size_t)gw * NH + lane * 2) = o;
}

// ---------------- gemm2: g = h @ W2, one thread per row ----------------

__global__ __launch_bounds__(256) void k_gemm2(const bf16* __restrict__ h,
                                               const float* __restrict__ W2,
                                               float* __restrict__ g) {
    __shared__ float sW[NH * NC];
    int t = threadIdx.x;
    for (int i = t; i < NH * NC; i += 256) sW[i] = W2[i];
    __syncthreads();
    int row = blockIdx.x * 256 + t;
    if (row >= NN) return;
    const bf16* hr = h + (size_t)row * NH;
    float acc[NC] = {};
    for (int kc = 0; kc < NH / 8; kc++) {
        bf16x8 hv = *(const bf16x8*)(hr + kc * 8);
#pragma unroll
        for (int j = 0; j < 8; j++) {
            float hx = (float)hv[j];
            const float* wr = &sW[(kc * 8 + j) * NC];
#pragma unroll
            for (int c = 0; c < NC; c++) acc[c] += hx * wr[c];
        }
    }
    float4* go = (float4*)(g + (size_t)row * NC);
    go[0] = make_float4(acc[0], acc[1], acc[2], acc[3]);
    go[1] = make_float4(acc[4], acc[5], acc[6], acc[7]);
    go[2] = make_float4(acc[8], acc[9], acc[10], acc[11]);
    go[3] = make_float4(acc[12], acc[13], acc[14], acc[15]);
}

// ---------------- spmm2 + bias + log_softmax fused ----------------
// one wave per node: lane = sub*16 + c; 4 edge subgroups x 16 classes,
// x2 unroll -> 8 row-gathers in flight; shfl-reduce; softmax in-register.

__global__ void k_spmm2(const int* __restrict__ row_off, const int2* __restrict__ edges,
                        const float* __restrict__ g, const float* __restrict__ b2,
                        float* __restrict__ out) {
    int node = (blockIdx.x * 256 + threadIdx.x) >> 6;
    int lane = threadIdx.x & 63;
    if (node >= NN) return;
    int c = lane & 15, sub = lane >> 4;
    int s = row_off[node], e = row_off[node + 1];

    float acc0 = 0.f, acc1 = 0.f;
    int i = s + sub;
    for (; i + 4 < e; i += 8) {
        int2 r0 = edges[i];
        int2 r1 = edges[i + 4];
        acc0 += __int_as_float(r0.y) * g[(size_t)r0.x * NC + c];
        acc1 += __int_as_float(r1.y) * g[(size_t)r1.x * NC + c];
    }
    if (i < e) {
        int2 r0 = edges[i];
        acc0 += __int_as_float(r0.y) * g[(size_t)r0.x * NC + c];
    }
    float acc = acc0 + acc1;
    // reduce across the 4 subgroups
    acc += __shfl_xor(acc, 16);
    acc += __shfl_xor(acc, 32);
    acc += b2[c];
    // log_softmax over the 16 classes (within each 16-lane group)
    float m = acc;
#pragma unroll
    for (int off = 1; off < 16; off <<= 1) m = fmaxf(m, __shfl_xor(m, off));
    float ex = __expf(acc - m);
    float sum = ex;
#pragma unroll
    for (int off = 1; off < 16; off <<= 1) sum += __shfl_xor(sum, off);
    float r = acc - m - __logf(sum);
    if (sub == 0) out[(size_t)node * NC + c] = r;
}

// ---------------- launch ----------------

extern "C" void kernel_launch(void* const* d_in, const int* in_sizes, int n_in,
                              void* d_out, int out_size, void* d_ws, size_t ws_size,
                              hipStream_t stream) {
    const float* x  = (const float*)d_in[0];
    const float* W1 = (const float*)d_in[1];
    const float* b1 = (const float*)d_in[2];
    const float* W2 = (const float*)d_in[3];
    const float* b2 = (const float*)d_in[4];
    const float* ew = (const float*)d_in[5];
    const int* src  = (const int*)d_in[6];
    const int* dst  = (const int*)d_in[7];
    float* out = (float*)d_out;

    char* ws = (char*)d_ws;
    bf16*  h0      = (bf16*)(ws + 0);              // 25,600,000
    bf16*  h       = (bf16*)(ws + 25600000);       // 25,600,000
    float* g       = (float*)(ws + 51200000);      // 6,400,000
    int*   row_off = (int*)(ws + 57600000);        // 400,016
    int*   cursor  = (int*)(ws + 58000016);        // 400,000
    int*   bsum    = (int*)(ws + 58400016);        // 512
    int2*  edges   = (int2*)(ws + 58400528);       // EE*8 = 25,600,000
    bf16*  W1T     = (bf16*)(ws + 84000528);       // 65,536

    hipMemsetAsync(cursor, 0, NN * sizeof(int), stream);
    k_hist<<<EE / 256, 256, 0, stream>>>(dst, cursor);
    k_scan1<<<NB_SCAN, 256, 0, stream>>>(cursor, row_off, bsum);
    k_scan2<<<1, 128, 0, stream>>>(bsum);
    k_scan3<<<NB_SCAN, 256, 0, stream>>>(row_off, cursor, bsum);
    k_fill<<<EE / 256, 256, 0, stream>>>(src, dst, ew, cursor, edges);

    k_cvtW1<<<(NF * NH) / 256, 256, 0, stream>>>(W1, W1T);
    k_gemm1<<<(NN + 63) / 64, 256, 0, stream>>>(x, W1T, h0);
    k_spmm1<<<(NN * 64) / 256, 256, 0, stream>>>(row_off, edges, h0, b1, h);

    k_gemm2<<<(NN + 255) / 256, 256, 0, stream>>>(h, W2, g);
    k_spmm2<<<(NN * 64) / 256, 256, 0, stream>>>(row_off, edges, g, b2, out);
}

// Round 3
// 709.346 us; speedup vs baseline: 1.3621x; 1.1677x over previous
//
#include <hip/hip_runtime.h>

#define NN 100000
#define EE 3200000
#define NF 256
#define NH 128
#define NC 16
#define NB_SCAN 98     // ceil(NN/1024)
#define NBKT 49        // ceil(NN/2048) buckets of 2048 dst nodes
#define BCAP 73728     // staging capacity per bucket (mean 65536, +32 sigma)
#define CHUNK 4096     // edges per k_bucket block

typedef __bf16 bf16;
typedef bf16 bf16x2 __attribute__((ext_vector_type(2)));
typedef bf16 bf16x8 __attribute__((ext_vector_type(8)));
typedef float f32x4 __attribute__((ext_vector_type(4)));

// ---------------- CSR build: 2-pass bucket sort ----------------

__global__ void k_init(int* __restrict__ bucket_cursor) {
    int t = threadIdx.x;
    if (t < NBKT) bucket_cursor[t] = t * BCAP;
}

// Pass 1: partition edges into NBKT staging regions, LDS-binned so global
// writes are contiguous runs per bucket (~700B avg) instead of 8B scatter.
__global__ __launch_bounds__(256) void k_bucket(const int* __restrict__ src,
                                                const int* __restrict__ dst,
                                                const float* __restrict__ ew,
                                                int* __restrict__ bucket_cursor,
                                                int2* __restrict__ staged) {
    __shared__ int2 recs[CHUNK];
    __shared__ unsigned char bkt[CHUNK];
    __shared__ int cnt[NBKT], start[NBKT + 1], gbase[NBKT];
    int t = threadIdx.x;
    int base = blockIdx.x * CHUNK;
    int n = EE - base; if (n > CHUNK) n = CHUNK;
    if (t < NBKT) cnt[t] = 0;
    __syncthreads();
    for (int i = t; i < n; i += 256) {
        int b = dst[base + i] >> 11;
        atomicAdd(&cnt[b], 1);
    }
    __syncthreads();
    if (t == 0) {
        int s = 0;
        for (int b = 0; b < NBKT; b++) { start[b] = s; s += cnt[b]; }
        start[NBKT] = s;
    }
    __syncthreads();
    if (t < NBKT) cnt[t] = start[t];   // reuse as LDS cursor
    __syncthreads();
    for (int i = t; i < n; i += 256) {
        int d = dst[base + i];
        int b = d >> 11;
        int p = atomicAdd(&cnt[b], 1);
        recs[p] = make_int2(src[base + i] | ((d & 2047) << 17), __float_as_int(ew[base + i]));
        bkt[p] = (unsigned char)b;
    }
    __syncthreads();
    if (t < NBKT) gbase[t] = atomicAdd(&bucket_cursor[t], start[t + 1] - start[t]);
    __syncthreads();
    for (int i = t; i < n; i += 256) {
        int b = bkt[i];
        staged[gbase[b] + (i - start[b])] = recs[i];
    }
}

// Per-node histogram from staged data: LDS atomics only (2048 counters/bucket).
__global__ __launch_bounds__(1024) void k_hist2(const int2* __restrict__ staged,
                                                const int* __restrict__ bucket_cursor,
                                                int* __restrict__ cnt_out) {
    __shared__ int c[2048];
    int t = threadIdx.x;
    int b = blockIdx.x;
    for (int i = t; i < 2048; i += 1024) c[i] = 0;
    __syncthreads();
    int s0 = b * BCAP, e0 = bucket_cursor[b];
    for (int i = s0 + t; i < e0; i += 1024) {
        atomicAdd(&c[staged[i].x >> 17], 1);
    }
    __syncthreads();
    int nb = b * 2048;
    for (int i = t; i < 2048; i += 1024) {
        int node = nb + i;
        if (node < NN) cnt_out[node] = c[i];
    }
}

__global__ void k_scan1(const int* __restrict__ cnt, int* __restrict__ row_off,
                        int* __restrict__ bsum) {
    __shared__ int s[256];
    int t = threadIdx.x;
    int base = blockIdx.x * 1024 + t * 4;
    int v0 = 0, v1 = 0, v2 = 0, v3 = 0;
    if (base + 3 < NN) {
        int4 c = *(const int4*)(cnt + base);
        v0 = c.x; v1 = c.y; v2 = c.z; v3 = c.w;
    } else {
        if (base     < NN) v0 = cnt[base];
        if (base + 1 < NN) v1 = cnt[base + 1];
        if (base + 2 < NN) v2 = cnt[base + 2];
        if (base + 3 < NN) v3 = cnt[base + 3];
    }
    int tsum = v0 + v1 + v2 + v3;
    s[t] = tsum;
    __syncthreads();
    for (int off = 1; off < 256; off <<= 1) {
        int xv = (t >= off) ? s[t - off] : 0;
        __syncthreads();
        s[t] += xv;
        __syncthreads();
    }
    if (t == 255) bsum[blockIdx.x] = s[255];
    int e0 = s[t] - tsum;
    int e1 = e0 + v0, e2 = e1 + v1, e3 = e2 + v2;
    if (base     < NN) row_off[base]     = e0;
    if (base + 1 < NN) row_off[base + 1] = e1;
    if (base + 2 < NN) row_off[base + 2] = e2;
    if (base + 3 < NN) row_off[base + 3] = e3;
}

__global__ void k_scan2(int* __restrict__ bsum) {
    __shared__ int s[128];
    int t = threadIdx.x;
    int v = (t < NB_SCAN) ? bsum[t] : 0;
    s[t] = v;
    __syncthreads();
    for (int off = 1; off < 128; off <<= 1) {
        int xv = (t >= off) ? s[t - off] : 0;
        __syncthreads();
        s[t] += xv;
        __syncthreads();
    }
    if (t < NB_SCAN) bsum[t] = s[t] - v;  // exclusive block offsets
}

__global__ void k_scan3(int* __restrict__ row_off, int* __restrict__ cursor,
                        const int* __restrict__ bsum) {
    int t = threadIdx.x;
    int add = bsum[blockIdx.x];
    int base = blockIdx.x * 1024 + t * 4;
#pragma unroll
    for (int j = 0; j < 4; j++) {
        int i = base + j;
        if (i < NN) {
            int v = row_off[i] + add;
            row_off[i] = v;
            cursor[i] = v;
        }
    }
    if (blockIdx.x == 0 && t == 0) row_off[NN] = EE;
}

// Pass 2: scatter staged records to final CSR position. Writes confined to
// each bucket's ~512KB window, cursor atomics to an 8KB window -> L2-resident.
__global__ __launch_bounds__(256) void k_scatter(const int2* __restrict__ staged,
                                                 const int* __restrict__ bucket_cursor,
                                                 int* __restrict__ cursor,
                                                 int2* __restrict__ edges) {
    int b = blockIdx.x;
    int s0 = b * BCAP;
    int n = bucket_cursor[b] - s0;
    int lo = s0 + (int)(((long long)n * blockIdx.y) >> 3);
    int hi = s0 + (int)(((long long)n * (blockIdx.y + 1)) >> 3);
    int nb = b << 11;
    for (int i = lo + threadIdx.x; i < hi; i += 256) {
        int2 r = staged[i];
        int d = nb + (r.x >> 17);
        int p = atomicAdd(&cursor[d], 1);
        edges[p] = make_int2(r.x & 0x1FFFF, r.y);
    }
}

// ---------------- layer 1: x @ W1 (bf16 MFMA) ----------------

__global__ void k_cvtW1(const float* __restrict__ W1, bf16* __restrict__ W1T) {
    int i = blockIdx.x * 256 + threadIdx.x;  // 32768 elems, W1 is [NF][NH]
    int k = i >> 7, n = i & 127;
    W1T[n * NF + k] = (bf16)W1[i];           // W1T: [NH][NF]
}

__global__ __launch_bounds__(256, 1) void k_gemm1(const float* __restrict__ x,
                                                  const bf16* __restrict__ W1T,
                                                  bf16* __restrict__ h0) {
    int lane = threadIdx.x & 63;
    int wid = threadIdx.x >> 6;
    int m = lane & 15;     // A row / D col within 16-tile
    int kg = lane >> 4;    // k-group 0..3
    int row = blockIdx.x * 64 + wid * 16 + m;
    bool in = (row < NN);
    const float* xr = x + (size_t)row * NF;

    bf16x8 a[8];
#pragma unroll
    for (int kt = 0; kt < 8; kt++) {
        int k0 = kt * 32 + kg * 8;
        float4 u = in ? *(const float4*)(xr + k0)     : make_float4(0.f, 0.f, 0.f, 0.f);
        float4 v = in ? *(const float4*)(xr + k0 + 4) : make_float4(0.f, 0.f, 0.f, 0.f);
        bf16x8 av = { (bf16)u.x, (bf16)u.y, (bf16)u.z, (bf16)u.w,
                      (bf16)v.x, (bf16)v.y, (bf16)v.z, (bf16)v.w };
        a[kt] = av;
    }

    f32x4 acc[8] = {};
#pragma unroll
    for (int ct = 0; ct < 8; ct++) {
        const bf16* bp = W1T + (size_t)(ct * 16 + m) * NF + kg * 8;
#pragma unroll
        for (int kt = 0; kt < 8; kt++) {
            bf16x8 b = *(const bf16x8*)(bp + kt * 32);
            acc[ct] = __builtin_amdgcn_mfma_f32_16x16x32_bf16(a[kt], b, acc[ct], 0, 0, 0);
        }
    }

    // D layout: col = lane&15, row = (lane>>4)*4 + reg
    int rbase = blockIdx.x * 64 + wid * 16 + kg * 4;
#pragma unroll
    for (int ct = 0; ct < 8; ct++) {
        int col = ct * 16 + m;
#pragma unroll
        for (int r = 0; r < 4; r++) {
            int rr = rbase + r;
            if (rr < NN) h0[(size_t)rr * NH + col] = (bf16)acc[ct][r];
        }
    }
}

// ---------------- spmm1: h = relu(A @ h0 + b1) ----------------
// one wave per node, 8 edges in flight (independent accumulators)

__global__ void k_spmm1(const int* __restrict__ row_off, const int2* __restrict__ edges,
                        const bf16* __restrict__ h0, const float* __restrict__ b1,
                        bf16* __restrict__ h) {
    int gw = (blockIdx.x * 256 + threadIdx.x) >> 6;  // node
    int lane = threadIdx.x & 63;
    if (gw >= NN) return;
    int s = row_off[gw], e = row_off[gw + 1];

    float ax[8], ay[8];
#pragma unroll
    for (int j = 0; j < 8; j++) { ax[j] = 0.f; ay[j] = 0.f; }

    int i = s;
    for (; i + 8 <= e; i += 8) {
        int2 r[8];
#pragma unroll
        for (int j = 0; j < 8; j++) r[j] = edges[i + j];
#pragma unroll
        for (int j = 0; j < 8; j++) {
            bf16x2 hv = *(const bf16x2*)(h0 + (size_t)r[j].x * NH + lane * 2);
            float w = __int_as_float(r[j].y);
            ax[j] += w * (float)hv[0];
            ay[j] += w * (float)hv[1];
        }
    }
    for (; i < e; i++) {
        int2 r = edges[i];
        bf16x2 hv = *(const bf16x2*)(h0 + (size_t)r.x * NH + lane * 2);
        float w = __int_as_float(r.y);
        ax[0] += w * (float)hv[0];
        ay[0] += w * (float)hv[1];
    }
    float sx = ((ax[0] + ax[1]) + (ax[2] + ax[3])) + ((ax[4] + ax[5]) + (ax[6] + ax[7]));
    float sy = ((ay[0] + ay[1]) + (ay[2] + ay[3])) + ((ay[4] + ay[5]) + (ay[6] + ay[7]));
    sx = fmaxf(sx + b1[lane * 2],     0.f);
    sy = fmaxf(sy + b1[lane * 2 + 1], 0.f);
    bf16x2 o = { (bf16)sx, (bf16)sy };
    *(bf16x2*)(h + (size_t)gw * NH + lane * 2) = o;
}

// ---------------- gemm2: g = h @ W2, one thread per row ----------------

__global__ __launch_bounds__(256) void k_gemm2(const bf16* __restrict__ h,
                                               const float* __restrict__ W2,
                                               float* __restrict__ g) {
    __shared__ float sW[NH * NC];
    int t = threadIdx.x;
    for (int i = t; i < NH * NC; i += 256) sW[i] = W2[i];
    __syncthreads();
    int row = blockIdx.x * 256 + t;
    if (row >= NN) return;
    const bf16* hr = h + (size_t)row * NH;
    float acc[NC] = {};
    for (int kc = 0; kc < NH / 8; kc++) {
        bf16x8 hv = *(const bf16x8*)(hr + kc * 8);
#pragma unroll
        for (int j = 0; j < 8; j++) {
            float hx = (float)hv[j];
            const float* wr = &sW[(kc * 8 + j) * NC];
#pragma unroll
            for (int c = 0; c < NC; c++) acc[c] += hx * wr[c];
        }
    }
    float4* go = (float4*)(g + (size_t)row * NC);
    go[0] = make_float4(acc[0], acc[1], acc[2], acc[3]);
    go[1] = make_float4(acc[4], acc[5], acc[6], acc[7]);
    go[2] = make_float4(acc[8], acc[9], acc[10], acc[11]);
    go[3] = make_float4(acc[12], acc[13], acc[14], acc[15]);
}

// ---------------- spmm2 + bias + log_softmax fused ----------------

__global__ void k_spmm2(const int* __restrict__ row_off, const int2* __restrict__ edges,
                        const float* __restrict__ g, const float* __restrict__ b2,
                        float* __restrict__ out) {
    int node = (blockIdx.x * 256 + threadIdx.x) >> 6;
    int lane = threadIdx.x & 63;
    if (node >= NN) return;
    int c = lane & 15, sub = lane >> 4;
    int s = row_off[node], e = row_off[node + 1];

    float acc0 = 0.f, acc1 = 0.f;
    int i = s + sub;
    for (; i + 4 < e; i += 8) {
        int2 r0 = edges[i];
        int2 r1 = edges[i + 4];
        acc0 += __int_as_float(r0.y) * g[(size_t)r0.x * NC + c];
        acc1 += __int_as_float(r1.y) * g[(size_t)r1.x * NC + c];
    }
    if (i < e) {
        int2 r0 = edges[i];
        acc0 += __int_as_float(r0.y) * g[(size_t)r0.x * NC + c];
    }
    float acc = acc0 + acc1;
    acc += __shfl_xor(acc, 16);
    acc += __shfl_xor(acc, 32);
    acc += b2[c];
    float m = acc;
#pragma unroll
    for (int off = 1; off < 16; off <<= 1) m = fmaxf(m, __shfl_xor(m, off));
    float ex = __expf(acc - m);
    float sum = ex;
#pragma unroll
    for (int off = 1; off < 16; off <<= 1) sum += __shfl_xor(sum, off);
    float r = acc - m - __logf(sum);
    if (sub == 0) out[(size_t)node * NC + c] = r;
}

// ---------------- launch ----------------

extern "C" void kernel_launch(void* const* d_in, const int* in_sizes, int n_in,
                              void* d_out, int out_size, void* d_ws, size_t ws_size,
                              hipStream_t stream) {
    const float* x  = (const float*)d_in[0];
    const float* W1 = (const float*)d_in[1];
    const float* b1 = (const float*)d_in[2];
    const float* W2 = (const float*)d_in[3];
    const float* b2 = (const float*)d_in[4];
    const float* ew = (const float*)d_in[5];
    const int* src  = (const int*)d_in[6];
    const int* dst  = (const int*)d_in[7];
    float* out = (float*)d_out;

    char* ws = (char*)d_ws;
    bf16*  h0      = (bf16*)(ws + 0);              // 25,600,000
    bf16*  h       = (bf16*)(ws + 25600000);       // 25,600,000
    float* g       = (float*)(ws + 51200000);      // 6,400,000
    int*   row_off = (int*)(ws + 57600000);        // 400,016
    int*   cursor  = (int*)(ws + 58000016);        // 400,000
    int*   bsum    = (int*)(ws + 58400016);        // 512
    int*   bucket_cursor = (int*)(ws + 58400528);  // 256
    int2*  edges   = (int2*)(ws + 58400784);       // EE*8 = 25,600,000
    bf16*  W1T     = (bf16*)(ws + 84000784);       // 65,536
    // staged aliases h (+ spills into g): both dead during CSR build
    int2*  staged  = (int2*)(ws + 25600000);       // NBKT*BCAP*8 = 28,901,376

    // CSR build (2-pass bucket sort)
    k_init<<<1, 64, 0, stream>>>(bucket_cursor);
    k_bucket<<<(EE + CHUNK - 1) / CHUNK, 256, 0, stream>>>(src, dst, ew, bucket_cursor, staged);
    k_hist2<<<NBKT, 1024, 0, stream>>>(staged, bucket_cursor, cursor);
    k_scan1<<<NB_SCAN, 256, 0, stream>>>(cursor, row_off, bsum);
    k_scan2<<<1, 128, 0, stream>>>(bsum);
    k_scan3<<<NB_SCAN, 256, 0, stream>>>(row_off, cursor, bsum);
    k_scatter<<<dim3(NBKT, 8), 256, 0, stream>>>(staged, bucket_cursor, cursor, edges);

    // layer 1
    k_cvtW1<<<(NF * NH) / 256, 256, 0, stream>>>(W1, W1T);
    k_gemm1<<<(NN + 63) / 64, 256, 0, stream>>>(x, W1T, h0);
    k_spmm1<<<(NN * 64) / 256, 256, 0, stream>>>(row_off, edges, h0, b1, h);

    // layer 2
    k_gemm2<<<(NN + 255) / 256, 256, 0, stream>>>(h, W2, g);
    k_spmm2<<<(NN * 64) / 256, 256, 0, stream>>>(row_off, edges, g, b2, out);
}

// Round 4
// 664.390 us; speedup vs baseline: 1.4543x; 1.0677x over previous
//
#include <hip/hip_runtime.h>

#define NN 100000
#define EE 3200000
#define NF 256
#define NH 128
#define NC 16
#define NB_SCAN 98     // ceil(NN/1024)
#define NBKT 196       // buckets of 512 dst nodes (NN/512 -> 196)
#define BCAP 20480     // staging capacity per bucket (mean 16327, +32 sigma)
#define CHUNK 4096     // edges per k_bucket block

typedef __bf16 bf16;
typedef bf16 bf16x2 __attribute__((ext_vector_type(2)));
typedef bf16 bf16x8 __attribute__((ext_vector_type(8)));
typedef float f32x4 __attribute__((ext_vector_type(4)));

// ---------------- CSR build: 2-pass bucket sort ----------------

__global__ void k_init(int* __restrict__ bucket_cursor) {
    int t = threadIdx.x;
    if (t < NBKT) bucket_cursor[t] = t * BCAP;
}

// Pass 1: partition edges into NBKT staging regions, LDS-binned so global
// writes are contiguous runs per bucket instead of 8B scatter.
__global__ __launch_bounds__(256) void k_bucket(const int* __restrict__ src,
                                                const int* __restrict__ dst,
                                                const float* __restrict__ ew,
                                                int* __restrict__ bucket_cursor,
                                                int2* __restrict__ staged) {
    __shared__ int2 recs[CHUNK];
    __shared__ unsigned char bkt[CHUNK];
    __shared__ int cnt[NBKT], start[NBKT + 1], cur[NBKT], gbase[NBKT], sc[256];
    int t = threadIdx.x;
    int base = blockIdx.x * CHUNK;
    int n = EE - base; if (n > CHUNK) n = CHUNK;
    if (t < NBKT) cnt[t] = 0;
    __syncthreads();
    for (int i = t; i < n; i += 256) {
        atomicAdd(&cnt[dst[base + i] >> 9], 1);
    }
    __syncthreads();
    // parallel exclusive scan of cnt -> start (Hillis-Steele over 256 slots)
    sc[t] = (t < NBKT) ? cnt[t] : 0;
    __syncthreads();
    for (int off = 1; off < 256; off <<= 1) {
        int v = (t >= off) ? sc[t - off] : 0;
        __syncthreads();
        sc[t] += v;
        __syncthreads();
    }
    if (t < NBKT) { start[t] = sc[t] - cnt[t]; cur[t] = sc[t] - cnt[t]; }
    if (t == 0) start[NBKT] = sc[255];
    __syncthreads();
    for (int i = t; i < n; i += 256) {
        int d = dst[base + i];
        int b = d >> 9;
        int p = atomicAdd(&cur[b], 1);
        recs[p] = make_int2(src[base + i] | ((d & 511) << 17), __float_as_int(ew[base + i]));
        bkt[p] = (unsigned char)b;
    }
    __syncthreads();
    if (t < NBKT) gbase[t] = atomicAdd(&bucket_cursor[t], start[t + 1] - start[t]);
    __syncthreads();
    for (int i = t; i < n; i += 256) {
        int b = bkt[i];
        staged[gbase[b] + (i - start[b])] = recs[i];
    }
}

// Per-node histogram from staged data: LDS atomics only (512 counters/bucket).
__global__ __launch_bounds__(256) void k_hist2(const int2* __restrict__ staged,
                                               const int* __restrict__ bucket_cursor,
                                               int* __restrict__ cnt_out) {
    __shared__ int c[512];
    int t = threadIdx.x;
    int b = blockIdx.x;
    for (int i = t; i < 512; i += 256) c[i] = 0;
    __syncthreads();
    int s0 = b * BCAP, e0 = bucket_cursor[b];
    for (int i = s0 + t; i < e0; i += 256) {
        atomicAdd(&c[staged[i].x >> 17], 1);
    }
    __syncthreads();
    int nb = b << 9;
    for (int i = t; i < 512; i += 256) {
        int node = nb + i;
        if (node < NN) cnt_out[node] = c[i];
    }
}

__global__ void k_scan1(const int* __restrict__ cnt, int* __restrict__ row_off,
                        int* __restrict__ bsum) {
    __shared__ int s[256];
    int t = threadIdx.x;
    int base = blockIdx.x * 1024 + t * 4;
    int v0 = 0, v1 = 0, v2 = 0, v3 = 0;
    if (base + 3 < NN) {
        int4 c = *(const int4*)(cnt + base);
        v0 = c.x; v1 = c.y; v2 = c.z; v3 = c.w;
    } else {
        if (base     < NN) v0 = cnt[base];
        if (base + 1 < NN) v1 = cnt[base + 1];
        if (base + 2 < NN) v2 = cnt[base + 2];
        if (base + 3 < NN) v3 = cnt[base + 3];
    }
    int tsum = v0 + v1 + v2 + v3;
    s[t] = tsum;
    __syncthreads();
    for (int off = 1; off < 256; off <<= 1) {
        int xv = (t >= off) ? s[t - off] : 0;
        __syncthreads();
        s[t] += xv;
        __syncthreads();
    }
    if (t == 255) bsum[blockIdx.x] = s[255];
    int e0 = s[t] - tsum;
    int e1 = e0 + v0, e2 = e1 + v1, e3 = e2 + v2;
    if (base     < NN) row_off[base]     = e0;
    if (base + 1 < NN) row_off[base + 1] = e1;
    if (base + 2 < NN) row_off[base + 2] = e2;
    if (base + 3 < NN) row_off[base + 3] = e3;
}

__global__ void k_scan2(int* __restrict__ bsum) {
    __shared__ int s[128];
    int t = threadIdx.x;
    int v = (t < NB_SCAN) ? bsum[t] : 0;
    s[t] = v;
    __syncthreads();
    for (int off = 1; off < 128; off <<= 1) {
        int xv = (t >= off) ? s[t - off] : 0;
        __syncthreads();
        s[t] += xv;
        __syncthreads();
    }
    if (t < NB_SCAN) bsum[t] = s[t] - v;  // exclusive block offsets
}

__global__ void k_scan3(int* __restrict__ row_off, int* __restrict__ cursor,
                        const int* __restrict__ bsum) {
    int t = threadIdx.x;
    int add = bsum[blockIdx.x];
    int base = blockIdx.x * 1024 + t * 4;
#pragma unroll
    for (int j = 0; j < 4; j++) {
        int i = base + j;
        if (i < NN) {
            int v = row_off[i] + add;
            row_off[i] = v;
            cursor[i] = v;
        }
    }
    if (blockIdx.x == 0 && t == 0) row_off[NN] = EE;
}

// Pass 2: ONE workgroup per bucket -> all writes to this bucket's ~128KB
// edge window come from one XCD's L2; lines fill completely before eviction.
__global__ __launch_bounds__(1024) void k_scatter(const int2* __restrict__ staged,
                                                  const int* __restrict__ bucket_cursor,
                                                  int* __restrict__ cursor,
                                                  int2* __restrict__ edges) {
    int b = blockIdx.x;
    int s0 = b * BCAP, e0 = bucket_cursor[b];
    int nb = b << 9;
    for (int i = s0 + threadIdx.x; i < e0; i += 1024) {
        int2 r = staged[i];
        int d = nb + (r.x >> 17);
        int p = atomicAdd(&cursor[d], 1);
        edges[p] = make_int2(r.x & 0x1FFFF, r.y);
    }
}

// ---------------- layer 1: x @ W1 (bf16 MFMA) ----------------

__global__ void k_cvtW1(const float* __restrict__ W1, bf16* __restrict__ W1T) {
    int i = blockIdx.x * 256 + threadIdx.x;  // 32768 elems, W1 is [NF][NH]
    int k = i >> 7, n = i & 127;
    W1T[n * NF + k] = (bf16)W1[i];           // W1T: [NH][NF]
}

__global__ __launch_bounds__(256, 1) void k_gemm1(const float* __restrict__ x,
                                                  const bf16* __restrict__ W1T,
                                                  bf16* __restrict__ h0) {
    int lane = threadIdx.x & 63;
    int wid = threadIdx.x >> 6;
    int m = lane & 15;     // A row / D col within 16-tile
    int kg = lane >> 4;    // k-group 0..3
    int row = blockIdx.x * 64 + wid * 16 + m;
    bool in = (row < NN);
    const float* xr = x + (size_t)row * NF;

    bf16x8 a[8];
#pragma unroll
    for (int kt = 0; kt < 8; kt++) {
        int k0 = kt * 32 + kg * 8;
        float4 u = in ? *(const float4*)(xr + k0)     : make_float4(0.f, 0.f, 0.f, 0.f);
        float4 v = in ? *(const float4*)(xr + k0 + 4) : make_float4(0.f, 0.f, 0.f, 0.f);
        bf16x8 av = { (bf16)u.x, (bf16)u.y, (bf16)u.z, (bf16)u.w,
                      (bf16)v.x, (bf16)v.y, (bf16)v.z, (bf16)v.w };
        a[kt] = av;
    }

    f32x4 acc[8] = {};
#pragma unroll
    for (int ct = 0; ct < 8; ct++) {
        const bf16* bp = W1T + (size_t)(ct * 16 + m) * NF + kg * 8;
#pragma unroll
        for (int kt = 0; kt < 8; kt++) {
            bf16x8 b = *(const bf16x8*)(bp + kt * 32);
            acc[ct] = __builtin_amdgcn_mfma_f32_16x16x32_bf16(a[kt], b, acc[ct], 0, 0, 0);
        }
    }

    // D layout: col = lane&15, row = (lane>>4)*4 + reg
    int rbase = blockIdx.x * 64 + wid * 16 + kg * 4;
#pragma unroll
    for (int ct = 0; ct < 8; ct++) {
        int col = ct * 16 + m;
#pragma unroll
        for (int r = 0; r < 4; r++) {
            int rr = rbase + r;
            if (rr < NN) h0[(size_t)rr * NH + col] = (bf16)acc[ct][r];
        }
    }
}

// ---------------- spmm1: h = relu(A @ h0 + b1) ----------------
// one wave per node, 8 edges in flight; fully predicated (no serial tail)

__global__ void k_spmm1(const int* __restrict__ row_off, const int2* __restrict__ edges,
                        const bf16* __restrict__ h0, const float* __restrict__ b1,
                        bf16* __restrict__ h) {
    int gw = (blockIdx.x * 256 + threadIdx.x) >> 6;  // node
    int lane = threadIdx.x & 63;
    if (gw >= NN) return;
    int s = row_off[gw], e = row_off[gw + 1];

    float ax[8], ay[8];
#pragma unroll
    for (int j = 0; j < 8; j++) { ax[j] = 0.f; ay[j] = 0.f; }

    for (int i = s; i < e; i += 8) {
        int2 r[8];
#pragma unroll
        for (int j = 0; j < 8; j++)
            r[j] = (i + j < e) ? edges[i + j] : make_int2(0, 0);  // w=0 for OOB
#pragma unroll
        for (int j = 0; j < 8; j++) {
            bf16x2 hv = *(const bf16x2*)(h0 + (size_t)r[j].x * NH + lane * 2);
            float w = __int_as_float(r[j].y);
            ax[j] += w * (float)hv[0];
            ay[j] += w * (float)hv[1];
        }
    }
    float sx = ((ax[0] + ax[1]) + (ax[2] + ax[3])) + ((ax[4] + ax[5]) + (ax[6] + ax[7]));
    float sy = ((ay[0] + ay[1]) + (ay[2] + ay[3])) + ((ay[4] + ay[5]) + (ay[6] + ay[7]));
    sx = fmaxf(sx + b1[lane * 2],     0.f);
    sy = fmaxf(sy + b1[lane * 2 + 1], 0.f);
    bf16x2 o = { (bf16)sx, (bf16)sy };
    *(bf16x2*)(h + (size_t)gw * NH + lane * 2) = o;
}

// ---------------- gemm2: g = h @ W2, one thread per row ----------------

__global__ __launch_bounds__(256) void k_gemm2(const bf16* __restrict__ h,
                                               const float* __restrict__ W2,
                                               float* __restrict__ g) {
    __shared__ float sW[NH * NC];
    int t = threadIdx.x;
    for (int i = t; i < NH * NC; i += 256) sW[i] = W2[i];
    __syncthreads();
    int row = blockIdx.x * 256 + t;
    if (row >= NN) return;
    const bf16* hr = h + (size_t)row * NH;
    float acc[NC] = {};
    for (int kc = 0; kc < NH / 8; kc++) {
        bf16x8 hv = *(const bf16x8*)(hr + kc * 8);
#pragma unroll
        for (int j = 0; j < 8; j++) {
            float hx = (float)hv[j];
            const float* wr = &sW[(kc * 8 + j) * NC];
#pragma unroll
            for (int c = 0; c < NC; c++) acc[c] += hx * wr[c];
        }
    }
    float4* go = (float4*)(g + (size_t)row * NC);
    go[0] = make_float4(acc[0], acc[1], acc[2], acc[3]);
    go[1] = make_float4(acc[4], acc[5], acc[6], acc[7]);
    go[2] = make_float4(acc[8], acc[9], acc[10], acc[11]);
    go[3] = make_float4(acc[12], acc[13], acc[14], acc[15]);
}

// ---------------- spmm2 + bias + log_softmax fused ----------------

__global__ void k_spmm2(const int* __restrict__ row_off, const int2* __restrict__ edges,
                        const float* __restrict__ g, const float* __restrict__ b2,
                        float* __restrict__ out) {
    int node = (blockIdx.x * 256 + threadIdx.x) >> 6;
    int lane = threadIdx.x & 63;
    if (node >= NN) return;
    int c = lane & 15, sub = lane >> 4;
    int s = row_off[node], e = row_off[node + 1];

    float acc0 = 0.f, acc1 = 0.f;
    int i = s + sub;
    for (; i + 4 < e; i += 8) {
        int2 r0 = edges[i];
        int2 r1 = edges[i + 4];
        acc0 += __int_as_float(r0.y) * g[(size_t)r0.x * NC + c];
        acc1 += __int_as_float(r1.y) * g[(size_t)r1.x * NC + c];
    }
    if (i < e) {
        int2 r0 = edges[i];
        acc0 += __int_as_float(r0.y) * g[(size_t)r0.x * NC + c];
    }
    float acc = acc0 + acc1;
    acc += __shfl_xor(acc, 16);
    acc += __shfl_xor(acc, 32);
    acc += b2[c];
    float m = acc;
#pragma unroll
    for (int off = 1; off < 16; off <<= 1) m = fmaxf(m, __shfl_xor(m, off));
    float ex = __expf(acc - m);
    float sum = ex;
#pragma unroll
    for (int off = 1; off < 16; off <<= 1) sum += __shfl_xor(sum, off);
    float r = acc - m - __logf(sum);
    if (sub == 0) out[(size_t)node * NC + c] = r;
}

// ---------------- launch ----------------

extern "C" void kernel_launch(void* const* d_in, const int* in_sizes, int n_in,
                              void* d_out, int out_size, void* d_ws, size_t ws_size,
                              hipStream_t stream) {
    const float* x  = (const float*)d_in[0];
    const float* W1 = (const float*)d_in[1];
    const float* b1 = (const float*)d_in[2];
    const float* W2 = (const float*)d_in[3];
    const float* b2 = (const float*)d_in[4];
    const float* ew = (const float*)d_in[5];
    const int* src  = (const int*)d_in[6];
    const int* dst  = (const int*)d_in[7];
    float* out = (float*)d_out;

    char* ws = (char*)d_ws;
    bf16*  h0      = (bf16*)(ws + 0);              // 25,600,000
    bf16*  h       = (bf16*)(ws + 25600000);       // 25,600,000
    float* g       = (float*)(ws + 51200000);      // 6,400,000
    int*   row_off = (int*)(ws + 57600000);        // 400,016
    int*   cursor  = (int*)(ws + 58000016);        // 400,000
    int*   bsum    = (int*)(ws + 58400016);        // 512
    int*   bucket_cursor = (int*)(ws + 58400528);  // 1024
    int2*  edges   = (int2*)(ws + 58401552);       // EE*8 = 25,600,000
    bf16*  W1T     = (bf16*)(ws + 84001552);       // 65,536
    // staged aliases h0 + low part of h: both dead during CSR build
    int2*  staged  = (int2*)(ws + 0);              // NBKT*BCAP*8 = 32,112,640

    // CSR build (2-pass bucket sort)
    k_init<<<1, 256, 0, stream>>>(bucket_cursor);
    k_bucket<<<(EE + CHUNK - 1) / CHUNK, 256, 0, stream>>>(src, dst, ew, bucket_cursor, staged);
    k_hist2<<<NBKT, 256, 0, stream>>>(staged, bucket_cursor, cursor);
    k_scan1<<<NB_SCAN, 256, 0, stream>>>(cursor, row_off, bsum);
    k_scan2<<<1, 128, 0, stream>>>(bsum);
    k_scan3<<<NB_SCAN, 256, 0, stream>>>(row_off, cursor, bsum);
    k_scatter<<<NBKT, 1024, 0, stream>>>(staged, bucket_cursor, cursor, edges);

    // layer 1
    k_cvtW1<<<(NF * NH) / 256, 256, 0, stream>>>(W1, W1T);
    k_gemm1<<<(NN + 63) / 64, 256, 0, stream>>>(x, W1T, h0);
    k_spmm1<<<(NN * 64) / 256, 256, 0, stream>>>(row_off, edges, h0, b1, h);

    // layer 2
    k_gemm2<<<(NN + 255) / 256, 256, 0, stream>>>(h, W2, g);
    k_spmm2<<<(NN * 64) / 256, 256, 0, stream>>>(row_off, edges, g, b2, out);
}

// Round 5
// 608.981 us; speedup vs baseline: 1.5866x; 1.0910x over previous
//
#include <hip/hip_runtime.h>

#define NN 100000
#define EE 3200000
#define NF 256
#define NH 128
#define NC 16
#define NB_SCAN 98     // ceil(NN/1024)
#define NBKT 196       // buckets of 512 dst nodes (NN/512 -> 196)
#define BCAP 20480     // staging capacity per bucket (mean 16327, +32 sigma)
#define CHUNK 4096     // edges per k_bucket block

typedef __bf16 bf16;
typedef bf16 bf16x2 __attribute__((ext_vector_type(2)));
typedef bf16 bf16x8 __attribute__((ext_vector_type(8)));
typedef float f32x4 __attribute__((ext_vector_type(4)));

// ---------------- CSR build: 2-pass bucket sort ----------------

__global__ void k_init(int* __restrict__ bucket_cursor, int2* __restrict__ edges) {
    int t = threadIdx.x;
    if (t < NBKT) bucket_cursor[t] = t * BCAP;
    if (t >= 224 && t < 240) edges[EE + t - 224] = make_int2(0, 0);  // pad for spmm overrun
}

// Pass 1: partition edges into NBKT staging regions, LDS-binned so global
// writes are contiguous runs per bucket instead of 8B scatter.
__global__ __launch_bounds__(256) void k_bucket(const int* __restrict__ src,
                                                const int* __restrict__ dst,
                                                const float* __restrict__ ew,
                                                int* __restrict__ bucket_cursor,
                                                int2* __restrict__ staged) {
    __shared__ int2 recs[CHUNK];
    __shared__ unsigned char bkt[CHUNK];
    __shared__ int cnt[NBKT], start[NBKT + 1], cur[NBKT], gbase[NBKT], sc[256];
    int t = threadIdx.x;
    int base = blockIdx.x * CHUNK;
    int n = EE - base; if (n > CHUNK) n = CHUNK;
    if (t < NBKT) cnt[t] = 0;
    __syncthreads();
    for (int i = t; i < n; i += 256) {
        atomicAdd(&cnt[dst[base + i] >> 9], 1);
    }
    __syncthreads();
    // parallel exclusive scan of cnt -> start (Hillis-Steele over 256 slots)
    sc[t] = (t < NBKT) ? cnt[t] : 0;
    __syncthreads();
    for (int off = 1; off < 256; off <<= 1) {
        int v = (t >= off) ? sc[t - off] : 0;
        __syncthreads();
        sc[t] += v;
        __syncthreads();
    }
    if (t < NBKT) { start[t] = sc[t] - cnt[t]; cur[t] = sc[t] - cnt[t]; }
    if (t == 0) start[NBKT] = sc[255];
    __syncthreads();
    for (int i = t; i < n; i += 256) {
        int d = dst[base + i];
        int b = d >> 9;
        int p = atomicAdd(&cur[b], 1);
        recs[p] = make_int2(src[base + i] | ((d & 511) << 17), __float_as_int(ew[base + i]));
        bkt[p] = (unsigned char)b;
    }
    __syncthreads();
    if (t < NBKT) gbase[t] = atomicAdd(&bucket_cursor[t], start[t + 1] - start[t]);
    __syncthreads();
    for (int i = t; i < n; i += 256) {
        int b = bkt[i];
        staged[gbase[b] + (i - start[b])] = recs[i];
    }
}

// Per-node histogram from staged data: LDS atomics only (512 counters/bucket).
__global__ __launch_bounds__(256) void k_hist2(const int2* __restrict__ staged,
                                               const int* __restrict__ bucket_cursor,
                                               int* __restrict__ cnt_out) {
    __shared__ int c[512];
    int t = threadIdx.x;
    int b = blockIdx.x;
    for (int i = t; i < 512; i += 256) c[i] = 0;
    __syncthreads();
    int s0 = b * BCAP, e0 = bucket_cursor[b];
    for (int i = s0 + t; i < e0; i += 256) {
        atomicAdd(&c[staged[i].x >> 17], 1);
    }
    __syncthreads();
    int nb = b << 9;
    for (int i = t; i < 512; i += 256) {
        int node = nb + i;
        if (node < NN) cnt_out[node] = c[i];
    }
}

__global__ void k_scan1(const int* __restrict__ cnt, int* __restrict__ row_off,
                        int* __restrict__ bsum) {
    __shared__ int s[256];
    int t = threadIdx.x;
    int base = blockIdx.x * 1024 + t * 4;
    int v0 = 0, v1 = 0, v2 = 0, v3 = 0;
    if (base + 3 < NN) {
        int4 c = *(const int4*)(cnt + base);
        v0 = c.x; v1 = c.y; v2 = c.z; v3 = c.w;
    } else {
        if (base     < NN) v0 = cnt[base];
        if (base + 1 < NN) v1 = cnt[base + 1];
        if (base + 2 < NN) v2 = cnt[base + 2];
        if (base + 3 < NN) v3 = cnt[base + 3];
    }
    int tsum = v0 + v1 + v2 + v3;
    s[t] = tsum;
    __syncthreads();
    for (int off = 1; off < 256; off <<= 1) {
        int xv = (t >= off) ? s[t - off] : 0;
        __syncthreads();
        s[t] += xv;
        __syncthreads();
    }
    if (t == 255) bsum[blockIdx.x] = s[255];
    int e0 = s[t] - tsum;
    int e1 = e0 + v0, e2 = e1 + v1, e3 = e2 + v2;
    if (base     < NN) row_off[base]     = e0;
    if (base + 1 < NN) row_off[base + 1] = e1;
    if (base + 2 < NN) row_off[base + 2] = e2;
    if (base + 3 < NN) row_off[base + 3] = e3;
}

__global__ void k_scan2(int* __restrict__ bsum) {
    __shared__ int s[128];
    int t = threadIdx.x;
    int v = (t < NB_SCAN) ? bsum[t] : 0;
    s[t] = v;
    __syncthreads();
    for (int off = 1; off < 128; off <<= 1) {
        int xv = (t >= off) ? s[t - off] : 0;
        __syncthreads();
        s[t] += xv;
        __syncthreads();
    }
    if (t < NB_SCAN) bsum[t] = s[t] - v;  // exclusive block offsets
}

__global__ void k_scan3(int* __restrict__ row_off, int* __restrict__ cursor,
                        const int* __restrict__ bsum) {
    int t = threadIdx.x;
    int add = bsum[blockIdx.x];
    int base = blockIdx.x * 1024 + t * 4;
#pragma unroll
    for (int j = 0; j < 4; j++) {
        int i = base + j;
        if (i < NN) {
            int v = row_off[i] + add;
            row_off[i] = v;
            cursor[i] = v;
        }
    }
    if (blockIdx.x == 0 && t == 0) row_off[NN] = EE;
}

// Pass 2: ONE workgroup per bucket -> all writes to this bucket's ~128KB
// edge window come from one XCD's L2; lines fill completely before eviction.
__global__ __launch_bounds__(1024) void k_scatter(const int2* __restrict__ staged,
                                                  const int* __restrict__ bucket_cursor,
                                                  int* __restrict__ cursor,
                                                  int2* __restrict__ edges) {
    int b = blockIdx.x;
    int s0 = b * BCAP, e0 = bucket_cursor[b];
    int nb = b << 9;
    for (int i = s0 + threadIdx.x; i < e0; i += 1024) {
        int2 r = staged[i];
        int d = nb + (r.x >> 17);
        int p = atomicAdd(&cursor[d], 1);
        edges[p] = make_int2(r.x & 0x1FFFF, r.y);
    }
}

// ---------------- layer 1: x @ W1 (bf16 MFMA) ----------------

__global__ void k_cvtW1(const float* __restrict__ W1, bf16* __restrict__ W1T) {
    int i = blockIdx.x * 256 + threadIdx.x;  // 32768 elems, W1 is [NF][NH]
    int k = i >> 7, n = i & 127;
    W1T[n * NF + k] = (bf16)W1[i];           // W1T: [NH][NF]
}

__global__ __launch_bounds__(256, 1) void k_gemm1(const float* __restrict__ x,
                                                  const bf16* __restrict__ W1T,
                                                  bf16* __restrict__ h0) {
    int lane = threadIdx.x & 63;
    int wid = threadIdx.x >> 6;
    int m = lane & 15;     // A row / D col within 16-tile
    int kg = lane >> 4;    // k-group 0..3
    int row = blockIdx.x * 64 + wid * 16 + m;
    bool in = (row < NN);
    const float* xr = x + (size_t)row * NF;

    bf16x8 a[8];
#pragma unroll
    for (int kt = 0; kt < 8; kt++) {
        int k0 = kt * 32 + kg * 8;
        float4 u = in ? *(const float4*)(xr + k0)     : make_float4(0.f, 0.f, 0.f, 0.f);
        float4 v = in ? *(const float4*)(xr + k0 + 4) : make_float4(0.f, 0.f, 0.f, 0.f);
        bf16x8 av = { (bf16)u.x, (bf16)u.y, (bf16)u.z, (bf16)u.w,
                      (bf16)v.x, (bf16)v.y, (bf16)v.z, (bf16)v.w };
        a[kt] = av;
    }

    f32x4 acc[8] = {};
#pragma unroll
    for (int ct = 0; ct < 8; ct++) {
        const bf16* bp = W1T + (size_t)(ct * 16 + m) * NF + kg * 8;
#pragma unroll
        for (int kt = 0; kt < 8; kt++) {
            bf16x8 b = *(const bf16x8*)(bp + kt * 32);
            acc[ct] = __builtin_amdgcn_mfma_f32_16x16x32_bf16(a[kt], b, acc[ct], 0, 0, 0);
        }
    }

    // D layout: col = lane&15, row = (lane>>4)*4 + reg
    int rbase = blockIdx.x * 64 + wid * 16 + kg * 4;
#pragma unroll
    for (int ct = 0; ct < 8; ct++) {
        int col = ct * 16 + m;
#pragma unroll
        for (int r = 0; r < 4; r++) {
            int rr = rbase + r;
            if (rr < NN) h0[(size_t)rr * NH + col] = (bf16)acc[ct][r];
        }
    }
}

// ---------------- spmm1: h = relu(A @ h0 + b1) ----------------
// one wave per node. Node/edge indices forced wave-uniform -> edge records
// come in via the SCALAR pipe (s_load), VALU only does gather+unpack+FMA.
// Reads up to 15 records past row end (valid next-row records or the zero
// pad after edges[EE]); their weights are scalar-zeroed.

__global__ __launch_bounds__(256) void k_spmm1(const int* __restrict__ row_off,
                                               const int2* __restrict__ edges,
                                               const bf16* __restrict__ h0,
                                               const float* __restrict__ b1,
                                               bf16* __restrict__ h) {
    int wid = __builtin_amdgcn_readfirstlane(threadIdx.x >> 6);
    int node = blockIdx.x * 4 + wid;               // wave-uniform, always < NN
    int lane = threadIdx.x & 63;
    int s = row_off[node], e = row_off[node + 1];  // uniform -> s_load

    const char* h0b = (const char*)h0;
    unsigned loff = (unsigned)lane * 4u;           // loop-invariant lane offset

    float ax[8], ay[8];
#pragma unroll
    for (int j = 0; j < 8; j++) { ax[j] = 0.f; ay[j] = 0.f; }

    for (int i = s; i < e; i += 16) {
        int2 q[16];
#pragma unroll
        for (int j = 0; j < 16; j++) q[j] = edges[i + j];   // uniform -> s_load
        unsigned dv[16];
#pragma unroll
        for (int j = 0; j < 16; j++) {
            const char* p = h0b + (((size_t)(unsigned)q[j].x << 8) + loff);
            dv[j] = *(const unsigned*)p;                     // 16 gathers in flight
        }
#pragma unroll
        for (int j = 0; j < 16; j++) {
            float w = (i + j < e) ? __int_as_float(q[j].y) : 0.f;  // scalar cselect
            float h0f = __int_as_float(dv[j] << 16);
            float h1f = __int_as_float(dv[j] & 0xffff0000u);
            ax[j & 7] += w * h0f;
            ay[j & 7] += w * h1f;
        }
    }
    float sx = ((ax[0] + ax[1]) + (ax[2] + ax[3])) + ((ax[4] + ax[5]) + (ax[6] + ax[7]));
    float sy = ((ay[0] + ay[1]) + (ay[2] + ay[3])) + ((ay[4] + ay[5]) + (ay[6] + ay[7]));
    sx = fmaxf(sx + b1[lane * 2],     0.f);
    sy = fmaxf(sy + b1[lane * 2 + 1], 0.f);
    bf16x2 o = { (bf16)sx, (bf16)sy };
    *(bf16x2*)(h + (size_t)node * NH + lane * 2) = o;
}

// ---------------- gemm2: g = h @ W2, one thread per row ----------------

__global__ __launch_bounds__(256) void k_gemm2(const bf16* __restrict__ h,
                                               const float* __restrict__ W2,
                                               float* __restrict__ g) {
    __shared__ float sW[NH * NC];
    int t = threadIdx.x;
    for (int i = t; i < NH * NC; i += 256) sW[i] = W2[i];
    __syncthreads();
    int row = blockIdx.x * 256 + t;
    if (row >= NN) return;
    const bf16* hr = h + (size_t)row * NH;
    float acc[NC] = {};
    for (int kc = 0; kc < NH / 8; kc++) {
        bf16x8 hv = *(const bf16x8*)(hr + kc * 8);
#pragma unroll
        for (int j = 0; j < 8; j++) {
            float hx = (float)hv[j];
            const float* wr = &sW[(kc * 8 + j) * NC];
#pragma unroll
            for (int c = 0; c < NC; c++) acc[c] += hx * wr[c];
        }
    }
    float4* go = (float4*)(g + (size_t)row * NC);
    go[0] = make_float4(acc[0], acc[1], acc[2], acc[3]);
    go[1] = make_float4(acc[4], acc[5], acc[6], acc[7]);
    go[2] = make_float4(acc[8], acc[9], acc[10], acc[11]);
    go[3] = make_float4(acc[12], acc[13], acc[14], acc[15]);
}

// ---------------- spmm2 + bias + log_softmax fused ----------------

__global__ void k_spmm2(const int* __restrict__ row_off, const int2* __restrict__ edges,
                        const float* __restrict__ g, const float* __restrict__ b2,
                        float* __restrict__ out) {
    int node = (blockIdx.x * 256 + threadIdx.x) >> 6;
    int lane = threadIdx.x & 63;
    if (node >= NN) return;
    int c = lane & 15, sub = lane >> 4;
    int s = row_off[node], e = row_off[node + 1];

    float acc0 = 0.f, acc1 = 0.f;
    int i = s + sub;
    for (; i + 4 < e; i += 8) {
        int2 r0 = edges[i];
        int2 r1 = edges[i + 4];
        acc0 += __int_as_float(r0.y) * g[(size_t)r0.x * NC + c];
        acc1 += __int_as_float(r1.y) * g[(size_t)r1.x * NC + c];
    }
    if (i < e) {
        int2 r0 = edges[i];
        acc0 += __int_as_float(r0.y) * g[(size_t)r0.x * NC + c];
    }
    float acc = acc0 + acc1;
    acc += __shfl_xor(acc, 16);
    acc += __shfl_xor(acc, 32);
    acc += b2[c];
    float m = acc;
#pragma unroll
    for (int off = 1; off < 16; off <<= 1) m = fmaxf(m, __shfl_xor(m, off));
    float ex = __expf(acc - m);
    float sum = ex;
#pragma unroll
    for (int off = 1; off < 16; off <<= 1) sum += __shfl_xor(sum, off);
    float r = acc - m - __logf(sum);
    if (sub == 0) out[(size_t)node * NC + c] = r;
}

// ---------------- launch ----------------

extern "C" void kernel_launch(void* const* d_in, const int* in_sizes, int n_in,
                              void* d_out, int out_size, void* d_ws, size_t ws_size,
                              hipStream_t stream) {
    const float* x  = (const float*)d_in[0];
    const float* W1 = (const float*)d_in[1];
    const float* b1 = (const float*)d_in[2];
    const float* W2 = (const float*)d_in[3];
    const float* b2 = (const float*)d_in[4];
    const float* ew = (const float*)d_in[5];
    const int* src  = (const int*)d_in[6];
    const int* dst  = (const int*)d_in[7];
    float* out = (float*)d_out;

    char* ws = (char*)d_ws;
    bf16*  h0      = (bf16*)(ws + 0);              // 25,600,000
    bf16*  h       = (bf16*)(ws + 25600000);       // 25,600,000
    float* g       = (float*)(ws + 51200000);      // 6,400,000
    int*   row_off = (int*)(ws + 57600000);        // 400,016
    int*   cursor  = (int*)(ws + 58000016);        // 400,000
    int*   bsum    = (int*)(ws + 58400016);        // 512
    int*   bucket_cursor = (int*)(ws + 58400528);  // 1024
    int2*  edges   = (int2*)(ws + 58401552);       // EE*8 + 128 pad = 25,600,128
    bf16*  W1T     = (bf16*)(ws + 84001680);       // 65,536
    // staged aliases h0 + low part of h: both dead during CSR build
    int2*  staged  = (int2*)(ws + 0);              // NBKT*BCAP*8 = 32,112,640

    // CSR build (2-pass bucket sort)
    k_init<<<1, 256, 0, stream>>>(bucket_cursor, edges);
    k_bucket<<<(EE + CHUNK - 1) / CHUNK, 256, 0, stream>>>(src, dst, ew, bucket_cursor, staged);
    k_hist2<<<NBKT, 256, 0, stream>>>(staged, bucket_cursor, cursor);
    k_scan1<<<NB_SCAN, 256, 0, stream>>>(cursor, row_off, bsum);
    k_scan2<<<1, 128, 0, stream>>>(bsum);
    k_scan3<<<NB_SCAN, 256, 0, stream>>>(row_off, cursor, bsum);
    k_scatter<<<NBKT, 1024, 0, stream>>>(staged, bucket_cursor, cursor, edges);

    // layer 1
    k_cvtW1<<<(NF * NH) / 256, 256, 0, stream>>>(W1, W1T);
    k_gemm1<<<(NN + 63) / 64, 256, 0, stream>>>(x, W1T, h0);
    k_spmm1<<<NN / 4, 256, 0, stream>>>(row_off, edges, h0, b1, h);

    // layer 2
    k_gemm2<<<(NN + 255) / 256, 256, 0, stream>>>(h, W2, g);
    k_spmm2<<<(NN * 64) / 256, 256, 0, stream>>>(row_off, edges, g, b2, out);
}

// Round 6
// 495.801 us; speedup vs baseline: 1.9488x; 1.2283x over previous
//
#include <hip/hip_runtime.h>

#define NN 100000
#define EE 3200000
#define NF 256
#define NH 128
#define NC 16
#define NBKT 391       // buckets of 256 dst nodes: ceil(100000/256)
#define BSZ 256        // nodes per bucket
#define BCAP 10240     // staging capacity per bucket (mean 8192, +22 sigma)
#define CHUNK 4096     // edges per k_bucket block

typedef __bf16 bf16;
typedef bf16 bf16x2 __attribute__((ext_vector_type(2)));
typedef bf16 bf16x8 __attribute__((ext_vector_type(8)));
typedef float f32x4 __attribute__((ext_vector_type(4)));

// ---------------- CSR build: bucket partition + per-bucket LDS sort ----------------

__global__ void k_init(int* __restrict__ bucket_cursor, int2* __restrict__ edges) {
    int t = threadIdx.x;
    if (t < NBKT) bucket_cursor[t] = t * BCAP;
    if (t >= 496) edges[EE + t - 496] = make_int2(0, 0);  // 16-record pad for spmm overrun
}

// Pass 1: partition edges into NBKT staging regions, LDS-binned so global
// writes are contiguous runs per bucket instead of 8B scatter.
__global__ __launch_bounds__(512) void k_bucket(const int* __restrict__ src,
                                                const int* __restrict__ dst,
                                                const float* __restrict__ ew,
                                                int* __restrict__ bucket_cursor,
                                                int2* __restrict__ staged) {
    __shared__ int2 recs[CHUNK];              // 32 KB
    __shared__ unsigned short bkt[CHUNK];     // 8 KB
    __shared__ int cnt[NBKT], start[NBKT + 1], cur[NBKT], gbase[NBKT];
    __shared__ int sc[512];
    int t = threadIdx.x;
    int base = blockIdx.x * CHUNK;
    int n = EE - base; if (n > CHUNK) n = CHUNK;
    if (t < NBKT) cnt[t] = 0;
    __syncthreads();
    for (int i = t; i < n; i += 512) {
        atomicAdd(&cnt[dst[base + i] >> 8], 1);
    }
    __syncthreads();
    sc[t] = (t < NBKT) ? cnt[t] : 0;
    __syncthreads();
    for (int off = 1; off < 512; off <<= 1) {
        int v = (t >= off) ? sc[t - off] : 0;
        __syncthreads();
        sc[t] += v;
        __syncthreads();
    }
    if (t < NBKT) { start[t] = sc[t] - cnt[t]; cur[t] = sc[t] - cnt[t]; }
    if (t == 0) start[NBKT] = sc[511];
    __syncthreads();
    for (int i = t; i < n; i += 512) {
        int d = dst[base + i];
        int b = d >> 8;
        int p = atomicAdd(&cur[b], 1);
        recs[p] = make_int2(src[base + i] | ((d & 255) << 17), __float_as_int(ew[base + i]));
        bkt[p] = (unsigned short)b;
    }
    __syncthreads();
    if (t < NBKT) gbase[t] = atomicAdd(&bucket_cursor[t], start[t + 1] - start[t]);
    __syncthreads();
    for (int i = t; i < n; i += 512) {
        int b = bkt[i];
        staged[gbase[b] + (i - start[b])] = recs[i];
    }
}

// Exclusive scan of per-bucket counts -> global base of each bucket in edges[].
__global__ void k_bscan(const int* __restrict__ bucket_cursor,
                        int* __restrict__ bucket_base, int* __restrict__ row_off) {
    __shared__ int s[512];
    int t = threadIdx.x;
    int v = (t < NBKT) ? (bucket_cursor[t] - t * BCAP) : 0;
    s[t] = v;
    __syncthreads();
    for (int off = 1; off < 512; off <<= 1) {
        int x = (t >= off) ? s[t - off] : 0;
        __syncthreads();
        s[t] += x;
        __syncthreads();
    }
    if (t < NBKT) bucket_base[t] = s[t] - v;
    if (t == 0) { bucket_base[NBKT] = EE; row_off[NN] = EE; }
}

// One block per bucket: LDS counting sort. Histogram + scan + row_off write +
// scatter all in one pass over staged; cursors are LDS atomics; global writes
// confined to this bucket's ~64KB window (one workgroup -> one XCD L2).
__global__ __launch_bounds__(1024) void k_sort(const int2* __restrict__ staged,
                                               const int* __restrict__ bucket_cursor,
                                               const int* __restrict__ bucket_base,
                                               int* __restrict__ row_off,
                                               int2* __restrict__ edges) {
    __shared__ int2 lrec[BCAP];               // 80 KB
    __shared__ int lcnt[BSZ], lstart[BSZ], lcur[BSZ];
    int t = threadIdx.x;
    int b = blockIdx.x;
    int n = bucket_cursor[b] - b * BCAP;
    int gb = bucket_base[b];
    const int2* sp = staged + (size_t)b * BCAP;
    if (t < BSZ) lcnt[t] = 0;
    __syncthreads();
    for (int i = t; i < n; i += 1024) {
        int2 r = sp[i];
        lrec[i] = r;
        atomicAdd(&lcnt[r.x >> 17], 1);
    }
    __syncthreads();
    if (t < BSZ) lstart[t] = lcnt[t];
    __syncthreads();
    for (int off = 1; off < BSZ; off <<= 1) {
        int v = 0;
        if (t < BSZ && t >= off) v = lstart[t - off];
        __syncthreads();
        if (t < BSZ) lstart[t] += v;
        __syncthreads();
    }
    if (t < BSZ) {
        int ex = lstart[t] - lcnt[t];        // exclusive within-bucket start
        lcur[t] = ex;
        int node = (b << 8) + t;
        if (node < NN) row_off[node] = gb + ex;
    }
    __syncthreads();
    for (int i = t; i < n; i += 1024) {
        int2 r = lrec[i];
        int d = r.x >> 17;
        int p = atomicAdd(&lcur[d], 1);
        edges[gb + p] = make_int2(r.x & 0x1FFFF, r.y);
    }
}

// ---------------- layer 1: x @ W1 (bf16 MFMA) ----------------

__global__ void k_cvtW1(const float* __restrict__ W1, bf16* __restrict__ W1T) {
    int i = blockIdx.x * 256 + threadIdx.x;  // 32768 elems, W1 is [NF][NH]
    int k = i >> 7, n = i & 127;
    W1T[n * NF + k] = (bf16)W1[i];           // W1T: [NH][NF]
}

__global__ __launch_bounds__(256, 1) void k_gemm1(const float* __restrict__ x,
                                                  const bf16* __restrict__ W1T,
                                                  bf16* __restrict__ h0) {
    int lane = threadIdx.x & 63;
    int wid = threadIdx.x >> 6;
    int m = lane & 15;     // A row / D col within 16-tile
    int kg = lane >> 4;    // k-group 0..3
    int row = blockIdx.x * 64 + wid * 16 + m;
    bool in = (row < NN);
    const float* xr = x + (size_t)row * NF;

    bf16x8 a[8];
#pragma unroll
    for (int kt = 0; kt < 8; kt++) {
        int k0 = kt * 32 + kg * 8;
        float4 u = in ? *(const float4*)(xr + k0)     : make_float4(0.f, 0.f, 0.f, 0.f);
        float4 v = in ? *(const float4*)(xr + k0 + 4) : make_float4(0.f, 0.f, 0.f, 0.f);
        bf16x8 av = { (bf16)u.x, (bf16)u.y, (bf16)u.z, (bf16)u.w,
                      (bf16)v.x, (bf16)v.y, (bf16)v.z, (bf16)v.w };
        a[kt] = av;
    }

    f32x4 acc[8] = {};
#pragma unroll
    for (int ct = 0; ct < 8; ct++) {
        const bf16* bp = W1T + (size_t)(ct * 16 + m) * NF + kg * 8;
#pragma unroll
        for (int kt = 0; kt < 8; kt++) {
            bf16x8 b = *(const bf16x8*)(bp + kt * 32);
            acc[ct] = __builtin_amdgcn_mfma_f32_16x16x32_bf16(a[kt], b, acc[ct], 0, 0, 0);
        }
    }

    // D layout: col = lane&15, row = (lane>>4)*4 + reg
    int rbase = blockIdx.x * 64 + wid * 16 + kg * 4;
#pragma unroll
    for (int ct = 0; ct < 8; ct++) {
        int col = ct * 16 + m;
#pragma unroll
        for (int r = 0; r < 4; r++) {
            int rr = rbase + r;
            if (rr < NN) h0[(size_t)rr * NH + col] = (bf16)acc[ct][r];
        }
    }
}

// ---------------- spmm1: h = relu(A @ h0 + b1) ----------------
// one wave per node. Edge records come in via the SCALAR pipe (s_load);
// OOB records (up to 15 past row end) get w=0 AND src=0 via scalar cselect,
// so pad gathers hit h0 row 0 (hot in L2) instead of fetching real rows.

__global__ __launch_bounds__(256) void k_spmm1(const int* __restrict__ row_off,
                                               const int2* __restrict__ edges,
                                               const bf16* __restrict__ h0,
                                               const float* __restrict__ b1,
                                               bf16* __restrict__ h) {
    int wid = __builtin_amdgcn_readfirstlane(threadIdx.x >> 6);
    int node = blockIdx.x * 4 + wid;               // wave-uniform, always < NN
    int lane = threadIdx.x & 63;
    int s = row_off[node], e = row_off[node + 1];  // uniform -> s_load

    const char* h0b = (const char*)h0;
    unsigned loff = (unsigned)lane * 4u;           // loop-invariant lane offset

    float ax[8], ay[8];
#pragma unroll
    for (int j = 0; j < 8; j++) { ax[j] = 0.f; ay[j] = 0.f; }

    for (int i = s; i < e; i += 16) {
        int2 q[16];
#pragma unroll
        for (int j = 0; j < 16; j++) q[j] = edges[i + j];   // uniform -> s_load
        unsigned sv[16];
        float wv[16];
#pragma unroll
        for (int j = 0; j < 16; j++) {
            bool v = (i + j) < e;                            // scalar cmp
            sv[j] = v ? (unsigned)q[j].x : 0u;               // s_cselect
            wv[j] = v ? __int_as_float(q[j].y) : 0.f;        // s_cselect
        }
        unsigned dv[16];
#pragma unroll
        for (int j = 0; j < 16; j++) {
            const char* p = h0b + (((size_t)sv[j] << 8) + loff);
            dv[j] = *(const unsigned*)p;                     // 16 gathers in flight
        }
#pragma unroll
        for (int j = 0; j < 16; j++) {
            float h0f = __int_as_float(dv[j] << 16);
            float h1f = __int_as_float(dv[j] & 0xffff0000u);
            ax[j & 7] += wv[j] * h0f;
            ay[j & 7] += wv[j] * h1f;
        }
    }
    float sx = ((ax[0] + ax[1]) + (ax[2] + ax[3])) + ((ax[4] + ax[5]) + (ax[6] + ax[7]));
    float sy = ((ay[0] + ay[1]) + (ay[2] + ay[3])) + ((ay[4] + ay[5]) + (ay[6] + ay[7]));
    sx = fmaxf(sx + b1[lane * 2],     0.f);
    sy = fmaxf(sy + b1[lane * 2 + 1], 0.f);
    bf16x2 o = { (bf16)sx, (bf16)sy };
    *(bf16x2*)(h + (size_t)node * NH + lane * 2) = o;
}

// ---------------- gemm2: g = h @ W2 (bf16 out), one thread per row ----------------

__global__ __launch_bounds__(256) void k_gemm2(const bf16* __restrict__ h,
                                               const float* __restrict__ W2,
                                               bf16* __restrict__ g) {
    __shared__ float sW[NH * NC];
    int t = threadIdx.x;
    for (int i = t; i < NH * NC; i += 256) sW[i] = W2[i];
    __syncthreads();
    int row = blockIdx.x * 256 + t;
    if (row >= NN) return;
    const bf16* hr = h + (size_t)row * NH;
    float acc[NC] = {};
    for (int kc = 0; kc < NH / 8; kc++) {
        bf16x8 hv = *(const bf16x8*)(hr + kc * 8);
#pragma unroll
        for (int j = 0; j < 8; j++) {
            float hx = (float)hv[j];
            const float* wr = &sW[(kc * 8 + j) * NC];
#pragma unroll
            for (int c = 0; c < NC; c++) acc[c] += hx * wr[c];
        }
    }
    bf16x8 o0 = { (bf16)acc[0], (bf16)acc[1], (bf16)acc[2],  (bf16)acc[3],
                  (bf16)acc[4], (bf16)acc[5], (bf16)acc[6],  (bf16)acc[7] };
    bf16x8 o1 = { (bf16)acc[8], (bf16)acc[9], (bf16)acc[10], (bf16)acc[11],
                  (bf16)acc[12], (bf16)acc[13], (bf16)acc[14], (bf16)acc[15] };
    bf16* gr = g + (size_t)row * NC;
    *(bf16x8*)gr = o0;
    *(bf16x8*)(gr + 8) = o1;
}

// ---------------- spmm2 + bias + log_softmax fused ----------------
// one wave per node: lane = sub*16 + c; 4 subgroups x 4-deep predicated ILP
// -> 16 edges in flight; g gathered as bf16 (32B/edge).

__global__ __launch_bounds__(256) void k_spmm2(const int* __restrict__ row_off,
                                               const int2* __restrict__ edges,
                                               const bf16* __restrict__ g,
                                               const float* __restrict__ b2,
                                               float* __restrict__ out) {
    int node = (blockIdx.x * 256 + threadIdx.x) >> 6;
    int lane = threadIdx.x & 63;
    int c = lane & 15, sub = lane >> 4;
    int s = row_off[node], e = row_off[node + 1];
    const unsigned short* gbp = (const unsigned short*)g;

    float acc[4] = { 0.f, 0.f, 0.f, 0.f };
    for (int i = s + sub; i < e; i += 16) {
        unsigned sx[4]; float w[4];
#pragma unroll
        for (int k = 0; k < 4; k++) {
            int idx = i + 4 * k;                 // <= e+11 <= EE+11: pad covers
            int2 r = edges[idx];
            bool v = idx < e;
            sx[k] = v ? (unsigned)r.x : 0u;
            w[k]  = v ? __int_as_float(r.y) : 0.f;
        }
#pragma unroll
        for (int k = 0; k < 4; k++) {
            unsigned hv = gbp[sx[k] * NC + c];
            acc[k] += w[k] * __int_as_float(hv << 16);
        }
    }
    float a = (acc[0] + acc[1]) + (acc[2] + acc[3]);
    a += __shfl_xor(a, 16);
    a += __shfl_xor(a, 32);
    a += b2[c];
    float m = a;
#pragma unroll
    for (int off = 1; off < 16; off <<= 1) m = fmaxf(m, __shfl_xor(m, off));
    float ex = __expf(a - m);
    float sum = ex;
#pragma unroll
    for (int off = 1; off < 16; off <<= 1) sum += __shfl_xor(sum, off);
    float r = a - m - __logf(sum);
    if (sub == 0) out[(size_t)node * NC + c] = r;
}

// ---------------- launch ----------------

extern "C" void kernel_launch(void* const* d_in, const int* in_sizes, int n_in,
                              void* d_out, int out_size, void* d_ws, size_t ws_size,
                              hipStream_t stream) {
    const float* x  = (const float*)d_in[0];
    const float* W1 = (const float*)d_in[1];
    const float* b1 = (const float*)d_in[2];
    const float* W2 = (const float*)d_in[3];
    const float* b2 = (const float*)d_in[4];
    const float* ew = (const float*)d_in[5];
    const int* src  = (const int*)d_in[6];
    const int* dst  = (const int*)d_in[7];
    float* out = (float*)d_out;

    char* ws = (char*)d_ws;
    bf16*  h0      = (bf16*)(ws + 0);              // 25,600,000
    bf16*  h       = (bf16*)(ws + 25600000);       // 25,600,000
    bf16*  g       = (bf16*)(ws + 51200000);       // NN*NC*2 = 3,200,000
    int*   row_off = (int*)(ws + 54400000);        // (NN+1)*4 = 400,004
    int*   bucket_cursor = (int*)(ws + 54800016);  // 1,564
    int*   bucket_base   = (int*)(ws + 54801584);  // 1,568
    int2*  edges   = (int2*)(ws + 54803168);       // EE*8 + 128 pad = 25,600,128
    bf16*  W1T     = (bf16*)(ws + 80403296);       // 65,536 -> end 80,468,832
    // staged aliases h0 + low part of h: dead before k_gemm1 writes h0
    int2*  staged  = (int2*)(ws + 0);              // NBKT*BCAP*8 = 32,030,720

    // CSR build
    k_init<<<1, 512, 0, stream>>>(bucket_cursor, edges);
    k_bucket<<<(EE + CHUNK - 1) / CHUNK, 512, 0, stream>>>(src, dst, ew, bucket_cursor, staged);
    k_bscan<<<1, 512, 0, stream>>>(bucket_cursor, bucket_base, row_off);
    k_sort<<<NBKT, 1024, 0, stream>>>(staged, bucket_cursor, bucket_base, row_off, edges);

    // layer 1
    k_cvtW1<<<(NF * NH) / 256, 256, 0, stream>>>(W1, W1T);
    k_gemm1<<<(NN + 63) / 64, 256, 0, stream>>>(x, W1T, h0);
    k_spmm1<<<NN / 4, 256, 0, stream>>>(row_off, edges, h0, b1, h);

    // layer 2
    k_gemm2<<<(NN + 255) / 256, 256, 0, stream>>>(h, W2, g);
    k_spmm2<<<NN / 4, 256, 0, stream>>>(row_off, edges, g, b2, out);
}